// Round 1
// baseline (1053.128 us; speedup 1.0000x reference)
//
#include <hip/hip_runtime.h>
#include <hip/hip_bf16.h>

#define B_  4
#define T_  2048
#define D_  2048
#define H_  16
#define DH_ 128

typedef __attribute__((ext_vector_type(4))) float f32x4;
typedef __attribute__((ext_vector_type(8))) short short8;

__device__ __forceinline__ ushort f2bf(float f) {
    unsigned int u = __builtin_bit_cast(unsigned int, f);
    u += 0x7fffu + ((u >> 16) & 1u);   // RNE
    return (ushort)(u >> 16);
}

// ---------------------------------------------------------------- cast x -> bf16
__global__ void cast_f32_bf16(const float* __restrict__ x, ushort* __restrict__ xb, int n) {
    int i = (blockIdx.x * 256 + threadIdx.x) * 4;
    if (i < n) {
        float4 v = *(const float4*)(x + i);
        ushort4 o;
        o.x = f2bf(v.x); o.y = f2bf(v.y); o.z = f2bf(v.z); o.w = f2bf(v.w);
        *(ushort4*)(xb + i) = o;
    }
}

// ------------------------------------------------- W [k][n] fp32 -> Wt [n][k] bf16
__global__ void transpose_cast(const float* __restrict__ W, ushort* __restrict__ Wt) {
    __shared__ float tile[32][33];
    int tx = threadIdx.x, ty = threadIdx.y;           // 32 x 8
    int n0 = blockIdx.x * 32, k0 = blockIdx.y * 32;
#pragma unroll
    for (int i = 0; i < 4; i++)
        tile[ty + i * 8][tx] = W[(size_t)(k0 + ty + i * 8) * D_ + n0 + tx];
    __syncthreads();
#pragma unroll
    for (int i = 0; i < 4; i++)
        Wt[(size_t)(n0 + ty + i * 8) * D_ + k0 + tx] = f2bf(tile[tx][ty + i * 8]);
}

// ---------------------------------------------------------------- GEMM C = A * Bt^T (+bias)
// A  [M][K] bf16 row-major, Bt [N][K] bf16 row-major.
// MODE 0: bf16 out row-major [M][N]
// MODE 1: f32  out row-major [M][N]
// MODE 2: bf16 out transposed per head: out[((b*H+h)*DH+dh)*T + t]  (V path)
template <int MODE>
__global__ __launch_bounds__(256, 2) void gemm_bt(
    const ushort* __restrict__ A, const ushort* __restrict__ Bt,
    const float* __restrict__ bias, void* __restrict__ Cout,
    int M, int N, int K)
{
    extern __shared__ char smem[];
    uint4* sA = (uint4*)smem;              // [128 rows][4 chunks] 16B chunks, chunk swizzled
    uint4* sB = (uint4*)(smem + 8192);

    const int tid  = threadIdx.x;
    const int row0 = blockIdx.y * 128, col0 = blockIdx.x * 128;

    // staging: thread -> (row mA, chunk g) ; 2 chunks each for A and B
    const int mA = tid >> 2, g = tid & 3;
    const uint4* pA0 = (const uint4*)(A + (size_t)(row0 + mA) * K + g * 8);
    const uint4* pA1 = (const uint4*)(A + (size_t)(row0 + mA + 64) * K + g * 8);
    const uint4* pB0 = (const uint4*)(Bt + (size_t)(col0 + mA) * K + g * 8);
    const uint4* pB1 = (const uint4*)(Bt + (size_t)(col0 + mA + 64) * K + g * 8);
    const int sw  = (mA >> 2) & 3;
    const int dst = mA * 4 + (g ^ sw);     // same swizzle for rows mA and mA+64
    uint4* qA0 = sA + dst;  uint4* qA1 = sA + dst + 256;
    uint4* qB0 = sB + dst;  uint4* qB1 = sB + dst + 256;

    const int lane = tid & 63, w = tid >> 6;
    const int l15 = lane & 15, quad = lane >> 4;
    const int wm = w & 1, wn = w >> 1;
    const int csel = quad ^ ((l15 >> 2) & 3);
    int aoff[4], boff[4];
#pragma unroll
    for (int mt = 0; mt < 4; mt++) aoff[mt] = (wm * 64 + mt * 16 + l15) * 4 + csel;
#pragma unroll
    for (int nt = 0; nt < 4; nt++) boff[nt] = (wn * 64 + nt * 16 + l15) * 4 + csel;

    f32x4 acc[4][4] = {};

    const int kIter = K >> 5;
    for (int kt = 0; kt < kIter; ++kt) {
        uint4 a0 = pA0[kt * 4], a1 = pA1[kt * 4];
        uint4 b0 = pB0[kt * 4], b1 = pB1[kt * 4];
        if (kt) __syncthreads();
        *qA0 = a0; *qA1 = a1; *qB0 = b0; *qB1 = b1;
        __syncthreads();
        short8 af[4], bfr[4];
#pragma unroll
        for (int mt = 0; mt < 4; mt++) af[mt]  = __builtin_bit_cast(short8, sA[aoff[mt]]);
#pragma unroll
        for (int nt = 0; nt < 4; nt++) bfr[nt] = __builtin_bit_cast(short8, sB[boff[nt]]);
#pragma unroll
        for (int mt = 0; mt < 4; mt++)
#pragma unroll
            for (int nt = 0; nt < 4; nt++)
                acc[mt][nt] = __builtin_amdgcn_mfma_f32_16x16x32_bf16(af[mt], bfr[nt], acc[mt][nt], 0, 0, 0);
    }

    if constexpr (MODE == 0 || MODE == 1) {
#pragma unroll
        for (int nt = 0; nt < 4; nt++) {
            int col = col0 + wn * 64 + nt * 16 + l15;
            float bb = bias[col];
#pragma unroll
            for (int mt = 0; mt < 4; mt++) {
                int rowb = row0 + wm * 64 + mt * 16 + quad * 4;
#pragma unroll
                for (int r = 0; r < 4; r++) {
                    float v = acc[mt][nt][r] + bb;
                    if constexpr (MODE == 0)
                        ((ushort*)Cout)[(size_t)(rowb + r) * N + col] = f2bf(v);
                    else
                        ((float*)Cout)[(size_t)(rowb + r) * N + col] = v;
                }
            }
        }
    } else {
        // V path: transpose 128x128 tile through LDS, emit [B,H,DH,T]
        __syncthreads();
        ushort* tr = (ushort*)smem;        // [128 dh][136] (pad 8 keeps uint4 alignment: 272B rows)
#pragma unroll
        for (int nt = 0; nt < 4; nt++) {
            int cl = wn * 64 + nt * 16 + l15;
            float bb = bias[col0 + cl];
#pragma unroll
            for (int mt = 0; mt < 4; mt++) {
                int rl = wm * 64 + mt * 16 + quad * 4;
#pragma unroll
                for (int r = 0; r < 4; r++)
                    tr[cl * 136 + rl + r] = f2bf(acc[mt][nt][r] + bb);
            }
        }
        __syncthreads();
        ushort* C = (ushort*)Cout;
        int b = row0 >> 11, t0 = row0 & (T_ - 1), h = col0 >> 7;
        for (int idx = tid; idx < 2048; idx += 256) {
            int dh = idx >> 4, c = idx & 15;
            uint4 v = *(const uint4*)(tr + dh * 136 + c * 8);
            *(uint4*)(C + (size_t)((b * H_ + h) * DH_ + dh) * T_ + t0 + c * 8) = v;
        }
    }
}

// ---------------------------------------------------------------- flash attention
// Q,K: [B,T,D] bf16 ; Vt: [B,H,DH,T] bf16 ; O: [B,T,D] bf16
__global__ __launch_bounds__(256, 2) void attn_kernel(
    const ushort* __restrict__ Q, const ushort* __restrict__ K,
    const ushort* __restrict__ Vt, ushort* __restrict__ O)
{
    __shared__ __align__(16) char smem[57344];
    uint4* qS = (uint4*)smem;                  // [64 rows][16 chunks] swizzled
    uint4* kS = (uint4*)(smem + 16384);        // [64][16]
    uint4* vS = (uint4*)(smem + 32768);        // [128][8]
    uint4* pS = (uint4*)(smem + 49152);        // [64][8]

    const int tid = threadIdx.x;
    const int qt = blockIdx.x, h = blockIdx.y, b = blockIdx.z;
    const int q0 = qt * 64;
    const int lane = tid & 63, w = tid >> 6, l15 = lane & 15, quad = lane >> 4;

    // stage Q once
    for (int idx = tid; idx < 1024; idx += 256) {
        int m = idx >> 4, c = idx & 15;
        qS[m * 16 + (c ^ (m & 7))] =
            *(const uint4*)(Q + ((size_t)(b * T_ + q0 + m)) * D_ + h * DH_ + c * 8);
    }

    f32x4 accO[8] = {};
    float mrow[4], lrow[4];
#pragma unroll
    for (int r = 0; r < 4; r++) { mrow[r] = -INFINITY; lrow[r] = 0.f; }
    const float scale = 0.08838834764831845f;   // 1/sqrt(128)

    for (int it = 0; it <= qt; ++it) {
        const int s0 = it * 64;
        __syncthreads();
        for (int idx = tid; idx < 1024; idx += 256) {
            int m = idx >> 4, c = idx & 15;
            kS[m * 16 + (c ^ (m & 7))] =
                *(const uint4*)(K + ((size_t)(b * T_ + s0 + m)) * D_ + h * DH_ + c * 8);
        }
        for (int idx = tid; idx < 1024; idx += 256) {
            int m = idx >> 3, c = idx & 7;
            vS[m * 8 + (c ^ (m & 7))] =
                *(const uint4*)(Vt + ((size_t)((b * H_ + h) * DH_ + m)) * T_ + s0 + c * 8);
        }
        __syncthreads();

        // S = Q K^T  (16 q-rows per wave x 64 s-cols)
        f32x4 s[4] = {};
        const int mq = w * 16 + l15;
#pragma unroll
        for (int ks = 0; ks < 4; ++ks) {
            short8 aq = __builtin_bit_cast(short8, qS[mq * 16 + ((ks * 4 + quad) ^ (mq & 7))]);
#pragma unroll
            for (int nt = 0; nt < 4; ++nt) {
                int n = nt * 16 + l15;
                short8 bk = __builtin_bit_cast(short8, kS[n * 16 + ((ks * 4 + quad) ^ (n & 7))]);
                s[nt] = __builtin_amdgcn_mfma_f32_16x16x32_bf16(aq, bk, s[nt], 0, 0, 0);
            }
        }

        // online softmax (rows = quad*4+r, cols across 16 lanes of the quad)
        float p[4][4];
#pragma unroll
        for (int r = 0; r < 4; r++) {
            int qrow = q0 + w * 16 + quad * 4 + r;
            float rmax = -INFINITY;
#pragma unroll
            for (int nt = 0; nt < 4; nt++) {
                int scol = s0 + nt * 16 + l15;
                float v = s[nt][r] * scale;
                v = (scol > qrow) ? -INFINITY : v;
                s[nt][r] = v;
                rmax = fmaxf(rmax, v);
            }
#pragma unroll
            for (int off = 1; off < 16; off <<= 1) rmax = fmaxf(rmax, __shfl_xor(rmax, off));
            float mnew  = fmaxf(mrow[r], rmax);
            float alpha = __expf(mrow[r] - mnew);
            mrow[r] = mnew;
            float sum = 0.f;
#pragma unroll
            for (int nt = 0; nt < 4; nt++) {
                float pv = __expf(s[nt][r] - mnew);
                p[nt][r] = pv; sum += pv;
            }
#pragma unroll
            for (int off = 1; off < 16; off <<= 1) sum += __shfl_xor(sum, off);
            lrow[r] = lrow[r] * alpha + sum;
#pragma unroll
            for (int nt = 0; nt < 8; nt++) accO[nt][r] *= alpha;
        }

        // write P (C-layout -> A-layout via LDS, own-wave region only)
#pragma unroll
        for (int nt = 0; nt < 4; nt++) {
            int col = nt * 16 + l15, c = col >> 3, ci = col & 7;
#pragma unroll
            for (int r = 0; r < 4; r++) {
                int m = w * 16 + quad * 4 + r;
                ((ushort*)pS)[(m * 8 + (c ^ (m & 7))) * 8 + ci] = f2bf(p[nt][r]);
            }
        }

        // O += P V   (k-dim = 64 s)
        const int mp = w * 16 + l15;
#pragma unroll
        for (int ks = 0; ks < 2; ++ks) {
            short8 ap = __builtin_bit_cast(short8, pS[mp * 8 + ((ks * 4 + quad) ^ (mp & 7))]);
#pragma unroll
            for (int nt = 0; nt < 8; nt++) {
                int n = nt * 16 + l15;
                short8 bv = __builtin_bit_cast(short8, vS[n * 8 + ((ks * 4 + quad) ^ (n & 7))]);
                accO[nt] = __builtin_amdgcn_mfma_f32_16x16x32_bf16(ap, bv, accO[nt], 0, 0, 0);
            }
        }
    }

    // epilogue: O / l
#pragma unroll
    for (int nt = 0; nt < 8; nt++) {
        int dh = nt * 16 + l15;
#pragma unroll
        for (int r = 0; r < 4; r++) {
            int t = q0 + w * 16 + quad * 4 + r;
            float v = accO[nt][r] / lrow[r];
            O[((size_t)(b * T_ + t)) * D_ + h * DH_ + dh] = f2bf(v);
        }
    }
}

extern "C" void kernel_launch(void* const* d_in, const int* in_sizes, int n_in,
                              void* d_out, int out_size, void* d_ws, size_t ws_size,
                              hipStream_t stream) {
    const float* x  = (const float*)d_in[0];
    const float* Wq = (const float*)d_in[1];
    const float* bq = (const float*)d_in[2];
    const float* Wk = (const float*)d_in[3];
    const float* bk = (const float*)d_in[4];
    const float* Wv = (const float*)d_in[5];
    const float* bv = (const float*)d_in[6];
    const float* Wo = (const float*)d_in[7];
    const float* bo = (const float*)d_in[8];

    char* ws = (char*)d_ws;
    const size_t MB = 1u << 20;
    ushort* xb  = (ushort*)(ws);
    ushort* Wqt = (ushort*)(ws + 32 * MB);
    ushort* Wkt = (ushort*)(ws + 40 * MB);
    ushort* Wvt = (ushort*)(ws + 48 * MB);
    ushort* Wot = (ushort*)(ws + 56 * MB);
    ushort* Qb  = (ushort*)(ws + 64 * MB);
    ushort* Kb  = (ushort*)(ws + 96 * MB);
    ushort* Vtb = (ushort*)(ws + 128 * MB);
    ushort* Ob  = (ushort*)(ws + 160 * MB);

    const int M = B_ * T_;   // 8192

    cast_f32_bf16<<<(M * D_) / 1024, 256, 0, stream>>>(x, xb, M * D_);
    dim3 tb(32, 8), tg(D_ / 32, D_ / 32);
    transpose_cast<<<tg, tb, 0, stream>>>(Wq, Wqt);
    transpose_cast<<<tg, tb, 0, stream>>>(Wk, Wkt);
    transpose_cast<<<tg, tb, 0, stream>>>(Wv, Wvt);
    transpose_cast<<<tg, tb, 0, stream>>>(Wo, Wot);

    dim3 gg(D_ / 128, M / 128);   // (16, 64)
    gemm_bt<0><<<gg, 256, 16384, stream>>>(xb, Wqt, bq, Qb,  M, D_, D_);
    gemm_bt<0><<<gg, 256, 16384, stream>>>(xb, Wkt, bk, Kb,  M, D_, D_);
    gemm_bt<2><<<gg, 256, 34816, stream>>>(xb, Wvt, bv, Vtb, M, D_, D_);

    attn_kernel<<<dim3(T_ / 64, H_, B_), 256, 0, stream>>>(Qb, Kb, Vtb, Ob);

    gemm_bt<1><<<gg, 256, 16384, stream>>>(Ob, Wot, bo, (float*)d_out, M, D_, D_);
}

// Round 2
// 682.951 us; speedup vs baseline: 1.5420x; 1.5420x over previous
//
#include <hip/hip_runtime.h>
#include <hip/hip_bf16.h>

#define B_  4
#define T_  2048
#define D_  2048
#define H_  16
#define DH_ 128

typedef __attribute__((ext_vector_type(4))) float f32x4;
typedef __attribute__((ext_vector_type(8))) short short8;

__device__ __forceinline__ ushort f2bf(float f) {
    unsigned int u = __builtin_bit_cast(unsigned int, f);
    u += 0x7fffu + ((u >> 16) & 1u);   // RNE
    return (ushort)(u >> 16);
}

// async global -> LDS, 16B per lane. LDS dst must be wave-uniform base + lane*16.
__device__ __forceinline__ void glds16(const void* g, void* l) {
    __builtin_amdgcn_global_load_lds(
        (const __attribute__((address_space(1))) unsigned int*)g,
        (__attribute__((address_space(3))) unsigned int*)l, 16, 0, 0);
}

// ---------------------------------------------------------------- cast x -> bf16
__global__ void cast_f32_bf16(const float* __restrict__ x, ushort* __restrict__ xb, int n) {
    int i = (blockIdx.x * 256 + threadIdx.x) * 4;
    if (i < n) {
        float4 v = *(const float4*)(x + i);
        ushort4 o;
        o.x = f2bf(v.x); o.y = f2bf(v.y); o.z = f2bf(v.z); o.w = f2bf(v.w);
        *(ushort4*)(xb + i) = o;
    }
}

// ------------------------------------------------- W [k][n] fp32 -> Wt [n][k] bf16
__global__ void transpose_cast(const float* __restrict__ W, ushort* __restrict__ Wt) {
    __shared__ float tile[32][33];
    int tx = threadIdx.x, ty = threadIdx.y;           // 32 x 8
    int n0 = blockIdx.x * 32, k0 = blockIdx.y * 32;
#pragma unroll
    for (int i = 0; i < 4; i++)
        tile[ty + i * 8][tx] = W[(size_t)(k0 + ty + i * 8) * D_ + n0 + tx];
    __syncthreads();
#pragma unroll
    for (int i = 0; i < 4; i++)
        Wt[(size_t)(n0 + ty + i * 8) * D_ + k0 + tx] = f2bf(tile[tx][ty + i * 8]);
}

// ---------------------------------------------------------------- GEMM C = (A * Bt^T + bias) * oscale
// A [M][K] bf16 row-major, Bt [N][K] bf16 row-major.
// MODE 0: bf16 out row-major ; MODE 1: f32 out row-major ; MODE 2: bf16 out [B,H,DH,T]
template <int MODE>
__global__ __launch_bounds__(256, 2) void gemm_bt(
    const ushort* __restrict__ A, const ushort* __restrict__ Bt,
    const float* __restrict__ bias, void* __restrict__ Cout,
    int M, int N, int K, float oscale)
{
    extern __shared__ char smem[];
    uint4* sA = (uint4*)smem;              // [128 rows][4 chunks], slot c holds chunk c^sw(row)
    uint4* sB = (uint4*)(smem + 8192);

    const int tid  = threadIdx.x;
    const int row0 = blockIdx.y * 128, col0 = blockIdx.x * 128;

    // staging: thread -> (row mA, slot g); global chunk g^sw so LDS reads are conflict-free
    const int mA = tid >> 2, g = tid & 3;
    const int gc = g ^ ((mA >> 2) & 3);
    const ushort* pa0 = A  + (size_t)(row0 + mA) * K + gc * 8;
    const ushort* pb0 = Bt + (size_t)(col0 + mA) * K + gc * 8;

    const int lane = tid & 63, w = tid >> 6;
    const int l15 = lane & 15, quad = lane >> 4;
    const int wm = w & 1, wn = w >> 1;
    const int csel = quad ^ ((l15 >> 2) & 3);
    int aoff[4], boff[4];
#pragma unroll
    for (int mt = 0; mt < 4; mt++) aoff[mt] = (wm * 64 + mt * 16 + l15) * 4 + csel;
#pragma unroll
    for (int nt = 0; nt < 4; nt++) boff[nt] = (wn * 64 + nt * 16 + l15) * 4 + csel;

    f32x4 acc[4][4] = {};

    const int kIter = K >> 5;
    for (int kt = 0; kt < kIter; ++kt) {
        if (kt) __syncthreads();
        glds16(pa0 + kt * 32,                     sA + tid);
        glds16(pa0 + kt * 32 + (size_t)64 * K,    sA + tid + 256);
        glds16(pb0 + kt * 32,                     sB + tid);
        glds16(pb0 + kt * 32 + (size_t)64 * K,    sB + tid + 256);
        __syncthreads();
        short8 af[4], bfr[4];
#pragma unroll
        for (int mt = 0; mt < 4; mt++) af[mt]  = __builtin_bit_cast(short8, sA[aoff[mt]]);
#pragma unroll
        for (int nt = 0; nt < 4; nt++) bfr[nt] = __builtin_bit_cast(short8, sB[boff[nt]]);
#pragma unroll
        for (int mt = 0; mt < 4; mt++)
#pragma unroll
            for (int nt = 0; nt < 4; nt++)
                acc[mt][nt] = __builtin_amdgcn_mfma_f32_16x16x32_bf16(af[mt], bfr[nt], acc[mt][nt], 0, 0, 0);
    }

    if constexpr (MODE == 0 || MODE == 1) {
#pragma unroll
        for (int nt = 0; nt < 4; nt++) {
            int col = col0 + wn * 64 + nt * 16 + l15;
            float bb = bias[col];
#pragma unroll
            for (int mt = 0; mt < 4; mt++) {
                int rowb = row0 + wm * 64 + mt * 16 + quad * 4;
#pragma unroll
                for (int r = 0; r < 4; r++) {
                    float v = (acc[mt][nt][r] + bb) * oscale;
                    if constexpr (MODE == 0)
                        ((ushort*)Cout)[(size_t)(rowb + r) * N + col] = f2bf(v);
                    else
                        ((float*)Cout)[(size_t)(rowb + r) * N + col] = v;
                }
            }
        }
    } else {
        // V path: transpose 128x128 tile through LDS, emit [B,H,DH,T]
        __syncthreads();
        ushort* tr = (ushort*)smem;        // [128 dh][136]
#pragma unroll
        for (int nt = 0; nt < 4; nt++) {
            int cl = wn * 64 + nt * 16 + l15;
            float bb = bias[col0 + cl];
#pragma unroll
            for (int mt = 0; mt < 4; mt++) {
                int rl = wm * 64 + mt * 16 + quad * 4;
#pragma unroll
                for (int r = 0; r < 4; r++)
                    tr[cl * 136 + rl + r] = f2bf(acc[mt][nt][r] + bb);
            }
        }
        __syncthreads();
        ushort* C = (ushort*)Cout;
        int b = row0 >> 11, t0 = row0 & (T_ - 1), h = col0 >> 7;
        for (int idx = tid; idx < 2048; idx += 256) {
            int dh = idx >> 4, c = idx & 15;
            uint4 v = *(const uint4*)(tr + dh * 136 + c * 8);
            *(uint4*)(C + (size_t)((b * H_ + h) * DH_ + dh) * T_ + t0 + c * 8) = v;
        }
    }
}

// ---------------------------------------------------------------- flash attention
// Q (pre-scaled), K: [B,T,D] bf16 ; Vt: [B,H,DH,T] bf16 ; O: [B,T,D] bf16
// Block: 256 threads, two q-tiles of 64 (qt, 31-qt) for load balance; s-tile 64.
__global__ __launch_bounds__(256, 4) void attn_kernel(
    const ushort* __restrict__ Q, const ushort* __restrict__ K,
    const ushort* __restrict__ Vt, ushort* __restrict__ O)
{
    __shared__ __align__(16) char smem[40960];
    uint4* kS = (uint4*)smem;                  // [64 s][16 chunks], swizzled via global side
    uint4* vS = (uint4*)(smem + 16384);        // [128 dh][8 chunks]
    uint4* pS = (uint4*)(smem + 32768);        // [64 q][8 chunks], wave-local

    const int tid = threadIdx.x;
    const int h = blockIdx.y, b = blockIdx.z;
    const int lane = tid & 63, w = tid >> 6, l15 = lane & 15, quad = lane >> 4;

    // staging bases (swizzle applied to global chunk index)
    const int krow = tid >> 4;                       // 0..15
    const int kchunk = (tid & 15) ^ (krow & 7);
    const ushort* kg = K + ((size_t)(b * T_) + krow) * D_ + h * DH_ + kchunk * 8;
    const int vrow = tid >> 3;                       // 0..31
    const int vchunk = (tid & 7) ^ (vrow & 7);
    const ushort* vg = Vt + ((size_t)((b * H_ + h) * DH_) + vrow) * T_ + vchunk * 8;

    const int qts[2] = { (int)blockIdx.x, 31 - (int)blockIdx.x };

    for (int e = 0; e < 2; ++e) {
        const int qt = qts[e], q0 = qt * 64;

        // Q A-fragments in registers (scale already folded into Q)
        short8 aq[4];
        {
            const ushort* qp = Q + ((size_t)(b * T_) + q0 + w * 16 + l15) * D_ + h * DH_ + quad * 8;
#pragma unroll
            for (int ks = 0; ks < 4; ++ks)
                aq[ks] = __builtin_bit_cast(short8, *(const uint4*)(qp + ks * 32));
        }

        f32x4 accO[8] = {};
        float mrow[4], lrow[4];
#pragma unroll
        for (int r = 0; r < 4; r++) { mrow[r] = -INFINITY; lrow[r] = 0.f; }

        for (int it = 0; it <= qt; ++it) {
            const int s0 = it * 64;
            __syncthreads();                          // prior tile's readers done
            const ushort* kp = kg + (size_t)s0 * D_;
            const ushort* vp = vg + s0;
#pragma unroll
            for (int j = 0; j < 4; ++j) glds16(kp + (size_t)j * 16 * D_, kS + j * 256 + tid);
#pragma unroll
            for (int j = 0; j < 4; ++j) glds16(vp + (size_t)j * 32 * T_, vS + j * 256 + tid);
            __syncthreads();                          // drains vmcnt -> tile ready

            // S = Q K^T  (16 q-rows per wave x 64 s)
            f32x4 s[4] = {};
#pragma unroll
            for (int ks = 0; ks < 4; ++ks)
#pragma unroll
                for (int nt = 0; nt < 4; ++nt) {
                    int n = nt * 16 + l15;
                    short8 bk = __builtin_bit_cast(short8, kS[n * 16 + ((ks * 4 + quad) ^ (n & 7))]);
                    s[nt] = __builtin_amdgcn_mfma_f32_16x16x32_bf16(aq[ks], bk, s[nt], 0, 0, 0);
                }

            // online softmax + P write (C-layout -> A-layout, wave-local LDS)
#pragma unroll
            for (int r = 0; r < 4; ++r) {
                const int qrow = q0 + w * 16 + quad * 4 + r;
                const int m = w * 16 + quad * 4 + r;
                float rmax = -INFINITY;
#pragma unroll
                for (int nt = 0; nt < 4; ++nt) {
                    float v = s[nt][r];
                    if (s0 + nt * 16 + l15 > qrow) v = -INFINITY;
                    s[nt][r] = v;
                    rmax = fmaxf(rmax, v);
                }
#pragma unroll
                for (int off = 1; off < 16; off <<= 1) rmax = fmaxf(rmax, __shfl_xor(rmax, off));
                float mnew  = fmaxf(mrow[r], rmax);
                float alpha = __expf(mrow[r] - mnew);
                mrow[r] = mnew;
                float sum = 0.f;
#pragma unroll
                for (int nt = 0; nt < 4; ++nt) {
                    float pv = __expf(s[nt][r] - mnew);
                    sum += pv;
                    int col = nt * 16 + l15;
                    ((ushort*)pS)[(m * 8 + ((col >> 3) ^ (m & 7))) * 8 + (col & 7)] = f2bf(pv);
                }
#pragma unroll
                for (int off = 1; off < 16; off <<= 1) sum += __shfl_xor(sum, off);
                lrow[r] = lrow[r] * alpha + sum;
#pragma unroll
                for (int nt = 0; nt < 8; ++nt) accO[nt][r] *= alpha;
            }

            // O += P V   (k-dim = 64)
            const int mp = w * 16 + l15;
#pragma unroll
            for (int ks = 0; ks < 2; ++ks) {
                short8 ap = __builtin_bit_cast(short8, pS[mp * 8 + ((ks * 4 + quad) ^ (mp & 7))]);
#pragma unroll
                for (int nt = 0; nt < 8; ++nt) {
                    int n = nt * 16 + l15;
                    short8 bv = __builtin_bit_cast(short8, vS[n * 8 + ((ks * 4 + quad) ^ (n & 7))]);
                    accO[nt] = __builtin_amdgcn_mfma_f32_16x16x32_bf16(ap, bv, accO[nt], 0, 0, 0);
                }
            }
        }

        // epilogue: O / l
#pragma unroll
        for (int nt = 0; nt < 8; ++nt) {
            int dh = nt * 16 + l15;
#pragma unroll
            for (int r = 0; r < 4; ++r) {
                int t = q0 + w * 16 + quad * 4 + r;
                O[((size_t)(b * T_ + t)) * D_ + h * DH_ + dh] = f2bf(accO[nt][r] / lrow[r]);
            }
        }
    }
}

extern "C" void kernel_launch(void* const* d_in, const int* in_sizes, int n_in,
                              void* d_out, int out_size, void* d_ws, size_t ws_size,
                              hipStream_t stream) {
    const float* x  = (const float*)d_in[0];
    const float* Wq = (const float*)d_in[1];
    const float* bq = (const float*)d_in[2];
    const float* Wk = (const float*)d_in[3];
    const float* bk = (const float*)d_in[4];
    const float* Wv = (const float*)d_in[5];
    const float* bv = (const float*)d_in[6];
    const float* Wo = (const float*)d_in[7];
    const float* bo = (const float*)d_in[8];

    char* ws = (char*)d_ws;
    const size_t MB = 1u << 20;
    ushort* xb  = (ushort*)(ws);
    ushort* Wqt = (ushort*)(ws + 32 * MB);
    ushort* Wkt = (ushort*)(ws + 40 * MB);
    ushort* Wvt = (ushort*)(ws + 48 * MB);
    ushort* Wot = (ushort*)(ws + 56 * MB);
    ushort* Qb  = (ushort*)(ws + 64 * MB);
    ushort* Kb  = (ushort*)(ws + 96 * MB);
    ushort* Vtb = (ushort*)(ws + 128 * MB);
    ushort* Ob  = (ushort*)(ws + 160 * MB);

    const int M = B_ * T_;   // 8192
    const float qscale = 0.08838834764831845f;  // 1/sqrt(DH)

    cast_f32_bf16<<<(M * D_) / 1024, 256, 0, stream>>>(x, xb, M * D_);
    dim3 tb(32, 8), tg(D_ / 32, D_ / 32);
    transpose_cast<<<tg, tb, 0, stream>>>(Wq, Wqt);
    transpose_cast<<<tg, tb, 0, stream>>>(Wk, Wkt);
    transpose_cast<<<tg, tb, 0, stream>>>(Wv, Wvt);
    transpose_cast<<<tg, tb, 0, stream>>>(Wo, Wot);

    dim3 gg(D_ / 128, M / 128);   // (16, 64)
    gemm_bt<0><<<gg, 256, 16384, stream>>>(xb, Wqt, bq, Qb,  M, D_, D_, qscale);
    gemm_bt<0><<<gg, 256, 16384, stream>>>(xb, Wkt, bk, Kb,  M, D_, D_, 1.0f);
    gemm_bt<2><<<gg, 256, 34816, stream>>>(xb, Wvt, bv, Vtb, M, D_, D_, 1.0f);

    attn_kernel<<<dim3(16, H_, B_), 256, 0, stream>>>(Qb, Kb, Vtb, Ob);

    gemm_bt<1><<<gg, 256, 16384, stream>>>(Ob, Wot, bo, (float*)d_out, M, D_, D_, 1.0f);
}

// Round 4
// 635.450 us; speedup vs baseline: 1.6573x; 1.0748x over previous
//
#include <hip/hip_runtime.h>
#include <hip/hip_bf16.h>

#define B_  4
#define T_  2048
#define D_  2048
#define H_  16
#define DH_ 128

typedef __attribute__((ext_vector_type(4))) float f32x4;
typedef __attribute__((ext_vector_type(8))) short short8;
typedef __attribute__((ext_vector_type(4))) _Float16 half4;

__device__ __forceinline__ ushort f2bf(float f) {
    unsigned int u = __builtin_bit_cast(unsigned int, f);
    u += 0x7fffu + ((u >> 16) & 1u);   // RNE
    return (ushort)(u >> 16);
}
__device__ __forceinline__ ushort f2h(float f) {
    return (ushort)(__builtin_bit_cast(unsigned int, __builtin_amdgcn_cvt_pkrtz(f, f)) & 0xffffu);
}

// async global -> LDS, 16B per lane. LDS dst must be wave-uniform base + lane*16.
__device__ __forceinline__ void glds16(const void* g, void* l) {
    __builtin_amdgcn_global_load_lds(
        (const __attribute__((address_space(1))) unsigned int*)g,
        (__attribute__((address_space(3))) unsigned int*)l, 16, 0, 0);
}

// ---------------------------------------------------------------- cast x -> bf16
__global__ void cast_f32_bf16(const float* __restrict__ x, ushort* __restrict__ xb, int n) {
    int i = (blockIdx.x * 256 + threadIdx.x) * 4;
    if (i < n) {
        float4 v = *(const float4*)(x + i);
        ushort4 o;
        o.x = f2bf(v.x); o.y = f2bf(v.y); o.z = f2bf(v.z); o.w = f2bf(v.w);
        *(ushort4*)(xb + i) = o;
    }
}

// ------------------------------------------------- W [k][n] fp32 -> Wt [n][k] bf16
__global__ void transpose_cast(const float* __restrict__ W, ushort* __restrict__ Wt) {
    __shared__ float tile[32][33];
    int tx = threadIdx.x, ty = threadIdx.y;           // 32 x 8
    int n0 = blockIdx.x * 32, k0 = blockIdx.y * 32;
#pragma unroll
    for (int i = 0; i < 4; i++)
        tile[ty + i * 8][tx] = W[(size_t)(k0 + ty + i * 8) * D_ + n0 + tx];
    __syncthreads();
#pragma unroll
    for (int i = 0; i < 4; i++)
        Wt[(size_t)(n0 + ty + i * 8) * D_ + k0 + tx] = f2bf(tile[tx][ty + i * 8]);
}

// ---------------------------------------------------------------- GEMM C = (A * Bt^T + bias) * oscale
// A [M][K] bf16 row-major, Bt [N][K] bf16 row-major.
// MODE 0: bf16 out row-major ; MODE 1: f32 out row-major ; MODE 2: f16 out [B,H,DH,T]
template <int MODE>
__global__ __launch_bounds__(256, 2) void gemm_bt(
    const ushort* __restrict__ A, const ushort* __restrict__ Bt,
    const float* __restrict__ bias, void* __restrict__ Cout,
    int M, int N, int K, float oscale)
{
    extern __shared__ char smem[];
    uint4* sA = (uint4*)smem;              // [128 rows][4 chunks], slot c holds chunk c^sw(row)
    uint4* sB = (uint4*)(smem + 8192);

    const int tid  = threadIdx.x;
    const int row0 = blockIdx.y * 128, col0 = blockIdx.x * 128;

    const int mA = tid >> 2, g = tid & 3;
    const int gc = g ^ ((mA >> 2) & 3);
    const ushort* pa0 = A  + (size_t)(row0 + mA) * K + gc * 8;
    const ushort* pb0 = Bt + (size_t)(col0 + mA) * K + gc * 8;

    const int lane = tid & 63, w = tid >> 6;
    const int l15 = lane & 15, quad = lane >> 4;
    const int wm = w & 1, wn = w >> 1;
    const int csel = quad ^ ((l15 >> 2) & 3);
    int aoff[4], boff[4];
#pragma unroll
    for (int mt = 0; mt < 4; mt++) aoff[mt] = (wm * 64 + mt * 16 + l15) * 4 + csel;
#pragma unroll
    for (int nt = 0; nt < 4; nt++) boff[nt] = (wn * 64 + nt * 16 + l15) * 4 + csel;

    f32x4 acc[4][4] = {};

    const int kIter = K >> 5;
    for (int kt = 0; kt < kIter; ++kt) {
        if (kt) __syncthreads();
        glds16(pa0 + kt * 32,                     sA + tid);
        glds16(pa0 + kt * 32 + (size_t)64 * K,    sA + tid + 256);
        glds16(pb0 + kt * 32,                     sB + tid);
        glds16(pb0 + kt * 32 + (size_t)64 * K,    sB + tid + 256);
        __syncthreads();
        short8 af[4], bfr[4];
#pragma unroll
        for (int mt = 0; mt < 4; mt++) af[mt]  = __builtin_bit_cast(short8, sA[aoff[mt]]);
#pragma unroll
        for (int nt = 0; nt < 4; nt++) bfr[nt] = __builtin_bit_cast(short8, sB[boff[nt]]);
#pragma unroll
        for (int mt = 0; mt < 4; mt++)
#pragma unroll
            for (int nt = 0; nt < 4; nt++)
                acc[mt][nt] = __builtin_amdgcn_mfma_f32_16x16x32_bf16(af[mt], bfr[nt], acc[mt][nt], 0, 0, 0);
    }

    if constexpr (MODE == 0 || MODE == 1) {
#pragma unroll
        for (int nt = 0; nt < 4; nt++) {
            int col = col0 + wn * 64 + nt * 16 + l15;
            float bb = bias[col];
#pragma unroll
            for (int mt = 0; mt < 4; mt++) {
                int rowb = row0 + wm * 64 + mt * 16 + quad * 4;
#pragma unroll
                for (int r = 0; r < 4; r++) {
                    float v = (acc[mt][nt][r] + bb) * oscale;
                    if constexpr (MODE == 0)
                        ((ushort*)Cout)[(size_t)(rowb + r) * N + col] = f2bf(v);
                    else
                        ((float*)Cout)[(size_t)(rowb + r) * N + col] = v;
                }
            }
        }
    } else {
        // V path: transpose 128x128 tile through LDS, emit f16 [B,H,DH,T]
        __syncthreads();
        ushort* tr = (ushort*)smem;        // [128 dh][136]
#pragma unroll
        for (int nt = 0; nt < 4; nt++) {
            int cl = wn * 64 + nt * 16 + l15;
            float bb = bias[col0 + cl];
#pragma unroll
            for (int mt = 0; mt < 4; mt++) {
                int rl = wm * 64 + mt * 16 + quad * 4;
#pragma unroll
                for (int r = 0; r < 4; r++)
                    tr[cl * 136 + rl + r] = f2h(acc[mt][nt][r] + bb);
            }
        }
        __syncthreads();
        ushort* C = (ushort*)Cout;
        int b = row0 >> 11, t0 = row0 & (T_ - 1), h = col0 >> 7;
        for (int idx = tid; idx < 2048; idx += 256) {
            int dh = idx >> 4, c = idx & 15;
            uint4 v = *(const uint4*)(tr + dh * 136 + c * 8);
            *(uint4*)(C + (size_t)((b * H_ + h) * DH_ + dh) * T_ + t0 + c * 8) = v;
        }
    }
}

// ---------------------------------------------------------------- flash attention (S^T / O^T form)
// Q (pre-scaled by 1/sqrt(DH)*log2e), K: [B,T,D] bf16 ; Vt: [B,H,DH,T] f16 ; O: [B,T,D] bf16
// grid 1024 (xcd-swizzled): two q-tiles of 64 (qx, 31-qx); s-tile 64.
// Wave w owns 16 q (cols). S^T = K·Q^T -> softmax rows are per-lane; P^T's C-layout
// == 16x16x16 B-frag layout -> PV directly from registers (f16), no LDS round-trip.
__global__ __launch_bounds__(256, 4) void attn_kernel(
    const ushort* __restrict__ Q, const ushort* __restrict__ K,
    const ushort* __restrict__ Vt, ushort* __restrict__ O)
{
    __shared__ __align__(16) char smem[32768];
    uint4* kS = (uint4*)smem;                  // [64 s][16 chunks], chunk-swizzled
    uint4* vS = (uint4*)(smem + 16384);        // [128 dh][8 chunks]

    const int tid = threadIdx.x;
    // XCD swizzle: all 16 q-blocks of head-group g land on xcd = g%8
    const int bid = blockIdx.x;
    const int slot = bid >> 3;
    const int g = (bid & 7) + 8 * (slot >> 4);
    const int qx = slot & 15;
    const int b = g >> 4, h = g & 15;

    const int lane = tid & 63, w = tid >> 6, l15 = lane & 15, quad = lane >> 4;

    // staging bases (swizzle on global chunk index)
    const int krow = tid >> 4;                       // 0..15
    const int kchunk = (tid & 15) ^ (krow & 7);
    const ushort* kg = K + ((size_t)(b * T_) + krow) * D_ + h * DH_ + kchunk * 8;
    const int vrow = tid >> 3;                       // 0..31
    const int vchunk = (tid & 7) ^ (vrow & 7);
    const ushort* vg = Vt + ((size_t)((b * H_ + h) * DH_) + vrow) * T_ + vchunk * 8;

    const int qts[2] = { qx, 31 - qx };

    for (int e = 0; e < 2; ++e) {
        const int qt = qts[e], q0 = qt * 64;
        const int qbase = q0 + w * 16;               // wave's first q

        // Q B-fragments in registers (B[k=quad*8+j][n=l15])
        short8 aq[4];
        {
            const ushort* qp = Q + ((size_t)(b * T_) + qbase + l15) * D_ + h * DH_ + quad * 8;
#pragma unroll
            for (int ks = 0; ks < 4; ++ks)
                aq[ks] = __builtin_bit_cast(short8, *(const uint4*)(qp + ks * 32));
        }

        f32x4 accO[8] = {};                          // O^T[dh=nt*16+quad*4+r][q=l15]
        float mrow = -INFINITY, lrow = 0.f;          // per-lane (per q)

        for (int it = 0; it <= qt; ++it) {
            const int s0 = it * 64;
            const int stMax = (it == qt) ? (w + 1) : 4;
            __syncthreads();                          // prior tile's readers done
            const ushort* kp = kg + (size_t)s0 * D_;
            const ushort* vp = vg + s0;
#pragma unroll
            for (int j = 0; j < 4; ++j) glds16(kp + (size_t)j * 16 * D_, kS + j * 256 + tid);
#pragma unroll
            for (int j = 0; j < 4; ++j) glds16(vp + (size_t)j * 32 * T_, vS + j * 256 + tid);
            __syncthreads();                          // tile ready

            // S^T = K Q^T : rows s (m from K), cols q
            f32x4 sT[4] = {};
#pragma unroll
            for (int ks = 0; ks < 4; ++ks)
#pragma unroll
                for (int st = 0; st < 4; ++st)
                    if (st < stMax) {
                        int row = st * 16 + l15;
                        short8 ak = __builtin_bit_cast(short8, kS[row * 16 + ((ks * 4 + quad) ^ (row & 7))]);
                        sT[st] = __builtin_amdgcn_mfma_f32_16x16x32_bf16(ak, aq[ks], sT[st], 0, 0, 0);
                    }

            // causal mask (only diagonal tiles need it; wave-uniform test)
            if (s0 + 64 > qbase) {
                const int q = qbase + l15;
#pragma unroll
                for (int st = 0; st < 4; ++st)
                    if (st < stMax)
#pragma unroll
                        for (int r = 0; r < 4; ++r)
                            if (s0 + st * 16 + quad * 4 + r > q) sT[st][r] = -INFINITY;
            }

            // online softmax: all per-lane except 2+2 quad-cross shfls
            float rmax = -INFINITY;
#pragma unroll
            for (int st = 0; st < 4; ++st)
                if (st < stMax)
#pragma unroll
                    for (int r = 0; r < 4; ++r) rmax = fmaxf(rmax, sT[st][r]);
            rmax = fmaxf(rmax, __shfl_xor(rmax, 16));
            rmax = fmaxf(rmax, __shfl_xor(rmax, 32));
            float mnew  = fmaxf(mrow, rmax);
            float alpha = __builtin_amdgcn_exp2f(mrow - mnew);
            mrow = mnew;

            float psum = 0.f;
            half4 pb[4];
#pragma unroll
            for (int st = 0; st < 4; ++st)
                if (st < stMax) {
                    float p0 = __builtin_amdgcn_exp2f(sT[st][0] - mnew);
                    float p1 = __builtin_amdgcn_exp2f(sT[st][1] - mnew);
                    float p2 = __builtin_amdgcn_exp2f(sT[st][2] - mnew);
                    float p3 = __builtin_amdgcn_exp2f(sT[st][3] - mnew);
                    psum += (p0 + p1) + (p2 + p3);
                    uint2 u;
                    u.x = __builtin_bit_cast(unsigned int, __builtin_amdgcn_cvt_pkrtz(p0, p1));
                    u.y = __builtin_bit_cast(unsigned int, __builtin_amdgcn_cvt_pkrtz(p2, p3));
                    pb[st] = __builtin_bit_cast(half4, u);
                }
            psum += __shfl_xor(psum, 16);
            psum += __shfl_xor(psum, 32);
            lrow = lrow * alpha + psum;
#pragma unroll
            for (int nt = 0; nt < 8; ++nt)
#pragma unroll
                for (int r = 0; r < 4; ++r) accO[nt][r] *= alpha;

            // O^T += V P^T : A = V[dh][s-16-tile] from LDS, B = pb[st] from regs
            const ushort* vbase = (const ushort*)vS;
#pragma unroll
            for (int st = 0; st < 4; ++st)
                if (st < stMax) {
                    const int ch = (st * 2 + (quad >> 1));
                    const int sub = (quad & 1) * 4;
#pragma unroll
                    for (int nt = 0; nt < 8; ++nt) {
                        int dh = nt * 16 + l15;
                        half4 vf = *(const half4*)(vbase + dh * 64 + ((ch ^ (l15 & 7)) * 8) + sub);
                        accO[nt] = __builtin_amdgcn_mfma_f32_16x16x16f16(vf, pb[st], accO[nt], 0, 0, 0);
                    }
                }
        }

        // epilogue: transpose O^T -> O via wave-private LDS, write bf16
        __syncthreads();                              // all waves done reading kS/vS
        ushort* eT = (ushort*)smem + w * 2176;        // [16 q][136 dh-pad]
        float inv = 1.0f / lrow;
#pragma unroll
        for (int nt = 0; nt < 8; ++nt) {
            int dh = nt * 16 + quad * 4;
#pragma unroll
            for (int r = 0; r < 4; ++r)
                eT[l15 * 136 + dh + r] = f2bf(accO[nt][r] * inv);
        }
        for (int idx = lane; idx < 256; idx += 64) {
            int row = idx >> 4, c = idx & 15;
            uint4 v = *(const uint4*)(eT + row * 136 + c * 8);
            *(uint4*)(O + ((size_t)(b * T_) + q0 + w * 16 + row) * D_ + h * DH_ + c * 8) = v;
        }
    }
}

extern "C" void kernel_launch(void* const* d_in, const int* in_sizes, int n_in,
                              void* d_out, int out_size, void* d_ws, size_t ws_size,
                              hipStream_t stream) {
    const float* x  = (const float*)d_in[0];
    const float* Wq = (const float*)d_in[1];
    const float* bq = (const float*)d_in[2];
    const float* Wk = (const float*)d_in[3];
    const float* bk = (const float*)d_in[4];
    const float* Wv = (const float*)d_in[5];
    const float* bv = (const float*)d_in[6];
    const float* Wo = (const float*)d_in[7];
    const float* bo = (const float*)d_in[8];

    char* ws = (char*)d_ws;
    const size_t MB = 1u << 20;
    ushort* xb  = (ushort*)(ws);
    ushort* Wqt = (ushort*)(ws + 32 * MB);
    ushort* Wkt = (ushort*)(ws + 40 * MB);
    ushort* Wvt = (ushort*)(ws + 48 * MB);
    ushort* Wot = (ushort*)(ws + 56 * MB);
    ushort* Qb  = (ushort*)(ws + 64 * MB);
    ushort* Kb  = (ushort*)(ws + 96 * MB);
    ushort* Vtb = (ushort*)(ws + 128 * MB);
    ushort* Ob  = (ushort*)(ws + 160 * MB);

    const int M = B_ * T_;   // 8192
    const float qscale = (float)(0.08838834764831845 * 1.4426950408889634); // 1/sqrt(DH) * log2(e)

    cast_f32_bf16<<<(M * D_) / 1024, 256, 0, stream>>>(x, xb, M * D_);
    dim3 tb(32, 8), tg(D_ / 32, D_ / 32);
    transpose_cast<<<tg, tb, 0, stream>>>(Wq, Wqt);
    transpose_cast<<<tg, tb, 0, stream>>>(Wk, Wkt);
    transpose_cast<<<tg, tb, 0, stream>>>(Wv, Wvt);
    transpose_cast<<<tg, tb, 0, stream>>>(Wo, Wot);

    dim3 gg(D_ / 128, M / 128);   // (16, 64)
    gemm_bt<0><<<gg, 256, 16384, stream>>>(xb, Wqt, bq, Qb,  M, D_, D_, qscale);
    gemm_bt<0><<<gg, 256, 16384, stream>>>(xb, Wkt, bk, Kb,  M, D_, D_, 1.0f);
    gemm_bt<2><<<gg, 256, 34816, stream>>>(xb, Wvt, bv, Vtb, M, D_, D_, 1.0f);

    attn_kernel<<<dim3(1024), 256, 0, stream>>>(Qb, Kb, Vtb, Ob);

    gemm_bt<1><<<gg, 256, 16384, stream>>>(Ob, Wot, bo, (float*)d_out, M, D_, D_, 1.0f);
}

// Round 5
// 616.686 us; speedup vs baseline: 1.7077x; 1.0304x over previous
//
#include <hip/hip_runtime.h>
#include <hip/hip_bf16.h>

#define B_  4
#define T_  2048
#define D_  2048
#define H_  16
#define DH_ 128

typedef __attribute__((ext_vector_type(4))) float f32x4;
typedef __attribute__((ext_vector_type(8))) short short8;
typedef __attribute__((ext_vector_type(4))) _Float16 half4;

__device__ __forceinline__ ushort f2bf(float f) {
    unsigned int u = __builtin_bit_cast(unsigned int, f);
    u += 0x7fffu + ((u >> 16) & 1u);   // RNE
    return (ushort)(u >> 16);
}
__device__ __forceinline__ ushort f2h(float f) {
    return (ushort)(__builtin_bit_cast(unsigned int, __builtin_amdgcn_cvt_pkrtz(f, f)) & 0xffffu);
}

// async global -> LDS, 16B per lane. LDS dst must be wave-uniform base + lane*16.
__device__ __forceinline__ void glds16(const void* g, void* l) {
    __builtin_amdgcn_global_load_lds(
        (const __attribute__((address_space(1))) unsigned int*)g,
        (__attribute__((address_space(3))) unsigned int*)l, 16, 0, 0);
}

// ---------------------------------------------------------------- cast x -> bf16
__global__ void cast_f32_bf16(const float* __restrict__ x, ushort* __restrict__ xb, int n) {
    int i = (blockIdx.x * 256 + threadIdx.x) * 4;
    if (i < n) {
        float4 v = *(const float4*)(x + i);
        ushort4 o;
        o.x = f2bf(v.x); o.y = f2bf(v.y); o.z = f2bf(v.z); o.w = f2bf(v.w);
        *(ushort4*)(xb + i) = o;
    }
}

// ------------------------------------------------- W [k][n] fp32 -> Wt [n][k] bf16
__global__ void transpose_cast(const float* __restrict__ W, ushort* __restrict__ Wt) {
    __shared__ float tile[32][33];
    int tx = threadIdx.x, ty = threadIdx.y;           // 32 x 8
    int n0 = blockIdx.x * 32, k0 = blockIdx.y * 32;
#pragma unroll
    for (int i = 0; i < 4; i++)
        tile[ty + i * 8][tx] = W[(size_t)(k0 + ty + i * 8) * D_ + n0 + tx];
    __syncthreads();
#pragma unroll
    for (int i = 0; i < 4; i++)
        Wt[(size_t)(n0 + ty + i * 8) * D_ + k0 + tx] = f2bf(tile[tx][ty + i * 8]);
}

// ---------------------------------------------------------------- merged QKV GEMM
// A [8192][2048] bf16; three weight mats [2048][2048] (row = out-col, b^T form).
// grid (48, 64): sel = x>>4 picks {Q,K,V}; V path emits f16 [B,H,DH,T].
__global__ __launch_bounds__(256, 3) void gemm_qkv(
    const ushort* __restrict__ A,
    const ushort* __restrict__ Wq, const ushort* __restrict__ Wk, const ushort* __restrict__ Wv,
    const float* __restrict__ bq, const float* __restrict__ bk, const float* __restrict__ bv,
    ushort* __restrict__ Qb, ushort* __restrict__ Kb, ushort* __restrict__ Vtb,
    float qscale)
{
    extern __shared__ char smem[];
    uint4* sA = (uint4*)smem;              // [128 rows][4 chunks], slot c holds chunk c^sw(row)
    uint4* sB = (uint4*)(smem + 8192);

    const int tid  = threadIdx.x;
    const int sel  = blockIdx.x >> 4;           // 0=Q 1=K 2=V
    const int row0 = blockIdx.y * 128, col0 = (blockIdx.x & 15) * 128;
    const ushort* Bt = (sel == 0) ? Wq : (sel == 1) ? Wk : Wv;
    const float* bias = (sel == 0) ? bq : (sel == 1) ? bk : bv;
    const float oscale = (sel == 0) ? qscale : 1.0f;
    const int K = D_, N = D_;

    const int mA = tid >> 2, g = tid & 3;
    const int gc = g ^ ((mA >> 2) & 3);
    const ushort* pa0 = A  + (size_t)(row0 + mA) * K + gc * 8;
    const ushort* pb0 = Bt + (size_t)(col0 + mA) * K + gc * 8;

    const int lane = tid & 63, w = tid >> 6;
    const int l15 = lane & 15, quad = lane >> 4;
    const int wm = w & 1, wn = w >> 1;
    const int csel = quad ^ ((l15 >> 2) & 3);
    int aoff[4], boff[4];
#pragma unroll
    for (int mt = 0; mt < 4; mt++) aoff[mt] = (wm * 64 + mt * 16 + l15) * 4 + csel;
#pragma unroll
    for (int nt = 0; nt < 4; nt++) boff[nt] = (wn * 64 + nt * 16 + l15) * 4 + csel;

    f32x4 acc[4][4] = {};

    const int kIter = K >> 5;
    for (int kt = 0; kt < kIter; ++kt) {
        if (kt) __syncthreads();
        glds16(pa0 + kt * 32,                     sA + tid);
        glds16(pa0 + kt * 32 + (size_t)64 * K,    sA + tid + 256);
        glds16(pb0 + kt * 32,                     sB + tid);
        glds16(pb0 + kt * 32 + (size_t)64 * K,    sB + tid + 256);
        __syncthreads();
        short8 af[4], bfr[4];
#pragma unroll
        for (int mt = 0; mt < 4; mt++) af[mt]  = __builtin_bit_cast(short8, sA[aoff[mt]]);
#pragma unroll
        for (int nt = 0; nt < 4; nt++) bfr[nt] = __builtin_bit_cast(short8, sB[boff[nt]]);
#pragma unroll
        for (int mt = 0; mt < 4; mt++)
#pragma unroll
            for (int nt = 0; nt < 4; nt++)
                acc[mt][nt] = __builtin_amdgcn_mfma_f32_16x16x32_bf16(af[mt], bfr[nt], acc[mt][nt], 0, 0, 0);
    }

    if (sel < 2) {
        ushort* Cout = (sel == 0) ? Qb : Kb;
#pragma unroll
        for (int nt = 0; nt < 4; nt++) {
            int col = col0 + wn * 64 + nt * 16 + l15;
            float bb = bias[col];
#pragma unroll
            for (int mt = 0; mt < 4; mt++) {
                int rowb = row0 + wm * 64 + mt * 16 + quad * 4;
#pragma unroll
                for (int r = 0; r < 4; r++)
                    Cout[(size_t)(rowb + r) * N + col] = f2bf((acc[mt][nt][r] + bb) * oscale);
            }
        }
    } else {
        // V path: transpose 128x128 tile through LDS, emit f16 [B,H,DH,T]
        __syncthreads();
        ushort* tr = (ushort*)smem;        // [128 dh][136]
#pragma unroll
        for (int nt = 0; nt < 4; nt++) {
            int cl = wn * 64 + nt * 16 + l15;
            float bb = bias[col0 + cl];
#pragma unroll
            for (int mt = 0; mt < 4; mt++) {
                int rl = wm * 64 + mt * 16 + quad * 4;
#pragma unroll
                for (int r = 0; r < 4; r++)
                    tr[cl * 136 + rl + r] = f2h(acc[mt][nt][r] + bb);
            }
        }
        __syncthreads();
        int b = row0 >> 11, t0 = row0 & (T_ - 1), h = col0 >> 7;
        for (int idx = tid; idx < 2048; idx += 256) {
            int dh = idx >> 4, c = idx & 15;
            uint4 v = *(const uint4*)(tr + dh * 136 + c * 8);
            *(uint4*)(Vtb + (size_t)((b * H_ + h) * DH_ + dh) * T_ + t0 + c * 8) = v;
        }
    }
}

// ---------------------------------------------------------------- O-projection GEMM (f32 out)
__global__ __launch_bounds__(256, 3) void gemm_bt_f32(
    const ushort* __restrict__ A, const ushort* __restrict__ Bt,
    const float* __restrict__ bias, float* __restrict__ Cout,
    int M, int N, int K)
{
    extern __shared__ char smem[];
    uint4* sA = (uint4*)smem;
    uint4* sB = (uint4*)(smem + 8192);

    const int tid  = threadIdx.x;
    const int row0 = blockIdx.y * 128, col0 = blockIdx.x * 128;

    const int mA = tid >> 2, g = tid & 3;
    const int gc = g ^ ((mA >> 2) & 3);
    const ushort* pa0 = A  + (size_t)(row0 + mA) * K + gc * 8;
    const ushort* pb0 = Bt + (size_t)(col0 + mA) * K + gc * 8;

    const int lane = tid & 63, w = tid >> 6;
    const int l15 = lane & 15, quad = lane >> 4;
    const int wm = w & 1, wn = w >> 1;
    const int csel = quad ^ ((l15 >> 2) & 3);
    int aoff[4], boff[4];
#pragma unroll
    for (int mt = 0; mt < 4; mt++) aoff[mt] = (wm * 64 + mt * 16 + l15) * 4 + csel;
#pragma unroll
    for (int nt = 0; nt < 4; nt++) boff[nt] = (wn * 64 + nt * 16 + l15) * 4 + csel;

    f32x4 acc[4][4] = {};

    const int kIter = K >> 5;
    for (int kt = 0; kt < kIter; ++kt) {
        if (kt) __syncthreads();
        glds16(pa0 + kt * 32,                     sA + tid);
        glds16(pa0 + kt * 32 + (size_t)64 * K,    sA + tid + 256);
        glds16(pb0 + kt * 32,                     sB + tid);
        glds16(pb0 + kt * 32 + (size_t)64 * K,    sB + tid + 256);
        __syncthreads();
        short8 af[4], bfr[4];
#pragma unroll
        for (int mt = 0; mt < 4; mt++) af[mt]  = __builtin_bit_cast(short8, sA[aoff[mt]]);
#pragma unroll
        for (int nt = 0; nt < 4; nt++) bfr[nt] = __builtin_bit_cast(short8, sB[boff[nt]]);
#pragma unroll
        for (int mt = 0; mt < 4; mt++)
#pragma unroll
            for (int nt = 0; nt < 4; nt++)
                acc[mt][nt] = __builtin_amdgcn_mfma_f32_16x16x32_bf16(af[mt], bfr[nt], acc[mt][nt], 0, 0, 0);
    }

#pragma unroll
    for (int nt = 0; nt < 4; nt++) {
        int col = col0 + wn * 64 + nt * 16 + l15;
        float bb = bias[col];
#pragma unroll
        for (int mt = 0; mt < 4; mt++) {
            int rowb = row0 + wm * 64 + mt * 16 + quad * 4;
#pragma unroll
            for (int r = 0; r < 4; r++)
                Cout[(size_t)(rowb + r) * N + col] = acc[mt][nt][r] + bb;
        }
    }
}

// ---------------------------------------------------------------- flash attention (S^T / O^T form)
// Q (pre-scaled by 1/sqrt(DH)*log2e), K: [B,T,D] bf16 ; Vt: [B,H,DH,T] f16 ; O: [B,T,D] bf16
// K staged via glds16 (chunk-swizzled); V staged via VGPRs into 8B-slot layout with
// slot ^= (dh&15): PV ds_read_b64 hits all 32 banks exactly once (perfect floor).
__global__ __launch_bounds__(256, 5) void attn_kernel(
    const ushort* __restrict__ Q, const ushort* __restrict__ K,
    const ushort* __restrict__ Vt, ushort* __restrict__ O)
{
    __shared__ __align__(16) char smem[32768];
    uint4*  kS = (uint4*)smem;                 // [64 s][16 chunks], chunk-swizzled
    ushort* vS = (ushort*)(smem + 16384);      // [128 dh][16 slots x 4 halfs], slot ^ (dh&15)

    const int tid = threadIdx.x;
    // XCD swizzle: all 16 q-blocks of head-group g land on xcd = g%8
    const int bid = blockIdx.x;
    const int slot = bid >> 3;
    const int g = (bid & 7) + 8 * (slot >> 4);
    const int qx = slot & 15;
    const int b = g >> 4, h = g & 15;

    const int lane = tid & 63, w = tid >> 6, l15 = lane & 15, quad = lane >> 4;

    const int krow = tid >> 4;                       // 0..15
    const int kchunk = (tid & 15) ^ (krow & 7);
    const ushort* kg = K + ((size_t)(b * T_) + krow) * D_ + h * DH_ + kchunk * 8;

    const int vrow = tid >> 3, vc = tid & 7;         // vrow 0..31, chunk 0..7 (8 halfs)
    const ushort* vg = Vt + ((size_t)((b * H_ + h) * DH_) + vrow) * T_ + vc * 8;
    const int vs0 = ((2 * vc    ) ^ (vrow & 15)) * 4;
    const int vs1 = ((2 * vc + 1) ^ (vrow & 15)) * 4;

    const int qts[2] = { qx, 31 - qx };

    for (int e = 0; e < 2; ++e) {
        const int qt = qts[e], q0 = qt * 64;
        const int qbase = q0 + w * 16;               // wave's first q

        // Q B-fragments in registers (B[k=quad*8+j][n=l15])
        short8 aq[4];
        {
            const ushort* qp = Q + ((size_t)(b * T_) + qbase + l15) * D_ + h * DH_ + quad * 8;
#pragma unroll
            for (int ks = 0; ks < 4; ++ks)
                aq[ks] = __builtin_bit_cast(short8, *(const uint4*)(qp + ks * 32));
        }

        f32x4 accO[8] = {};                          // O^T[dh=nt*16+quad*4+r][q=l15]
        float mrow = -INFINITY, lrow = 0.f;          // per-lane (per q)

        auto tile = [&](int s0, int stMax, bool diag) {
            __syncthreads();                          // prior tile's readers done
            const ushort* kp = kg + (size_t)s0 * D_;
#pragma unroll
            for (int j = 0; j < 4; ++j) glds16(kp + (size_t)j * 16 * D_, kS + j * 256 + tid);
            // V: global -> VGPR -> swizzled LDS slots
            const ushort* vp = vg + s0;
            uint4 vv[4];
#pragma unroll
            for (int j = 0; j < 4; ++j) vv[j] = *(const uint4*)(vp + (size_t)j * 32 * T_);
#pragma unroll
            for (int j = 0; j < 4; ++j) {
                ushort* dst = vS + (j * 32 + vrow) * 64;
                *(uint2*)(dst + vs0) = make_uint2(vv[j].x, vv[j].y);
                *(uint2*)(dst + vs1) = make_uint2(vv[j].z, vv[j].w);
            }
            __syncthreads();                          // tile ready

            // S^T = K Q^T : rows s (from K), cols q
            f32x4 sT[4] = {};
#pragma unroll
            for (int ks = 0; ks < 4; ++ks)
#pragma unroll
                for (int st = 0; st < 4; ++st)
                    if (st < stMax) {
                        int row = st * 16 + l15;
                        short8 ak = __builtin_bit_cast(short8, kS[row * 16 + ((ks * 4 + quad) ^ (row & 7))]);
                        sT[st] = __builtin_amdgcn_mfma_f32_16x16x32_bf16(ak, aq[ks], sT[st], 0, 0, 0);
                    }

            // causal mask: only the st==w subtile straddles the diagonal
            if (diag) {
                const int q = qbase + l15;
                const int st = stMax - 1;
#pragma unroll
                for (int r = 0; r < 4; ++r)
                    if (s0 + st * 16 + quad * 4 + r > q) sT[st][r] = -INFINITY;
            }

            // online softmax: per-lane rows, 2+2 quad-cross shfls
            float rmax = -INFINITY;
#pragma unroll
            for (int st = 0; st < 4; ++st)
                if (st < stMax)
#pragma unroll
                    for (int r = 0; r < 4; ++r) rmax = fmaxf(rmax, sT[st][r]);
            rmax = fmaxf(rmax, __shfl_xor(rmax, 16));
            rmax = fmaxf(rmax, __shfl_xor(rmax, 32));
            float mnew  = fmaxf(mrow, rmax);
            float alpha = __builtin_amdgcn_exp2f(mrow - mnew);
            mrow = mnew;

            float psum = 0.f;
            half4 pb[4];
#pragma unroll
            for (int st = 0; st < 4; ++st)
                if (st < stMax) {
                    float p0 = __builtin_amdgcn_exp2f(sT[st][0] - mnew);
                    float p1 = __builtin_amdgcn_exp2f(sT[st][1] - mnew);
                    float p2 = __builtin_amdgcn_exp2f(sT[st][2] - mnew);
                    float p3 = __builtin_amdgcn_exp2f(sT[st][3] - mnew);
                    psum += (p0 + p1) + (p2 + p3);
                    uint2 u;
                    u.x = __builtin_bit_cast(unsigned int, __builtin_amdgcn_cvt_pkrtz(p0, p1));
                    u.y = __builtin_bit_cast(unsigned int, __builtin_amdgcn_cvt_pkrtz(p2, p3));
                    pb[st] = __builtin_bit_cast(half4, u);
                }
            psum += __shfl_xor(psum, 16);
            psum += __shfl_xor(psum, 32);
            lrow = lrow * alpha + psum;
#pragma unroll
            for (int nt = 0; nt < 8; ++nt)
#pragma unroll
                for (int r = 0; r < 4; ++r) accO[nt][r] *= alpha;

            // O^T += V P^T : A-frag = V[dh][s16: quad*4..+4] (b64, conflict-free), B = pb
#pragma unroll
            for (int st = 0; st < 4; ++st)
                if (st < stMax) {
#pragma unroll
                    for (int nt = 0; nt < 8; ++nt) {
                        int dh = nt * 16 + l15;
                        half4 vf = *(const half4*)(vS + dh * 64 + (((st * 4 + quad) ^ l15) * 4));
                        accO[nt] = __builtin_amdgcn_mfma_f32_16x16x16f16(vf, pb[st], accO[nt], 0, 0, 0);
                    }
                }
        };

        for (int it = 0; it < qt; ++it) tile(it * 64, 4, false);
        tile(qt * 64, w + 1, true);

        // epilogue: transpose O^T -> O via wave-private LDS, write bf16
        __syncthreads();                              // all waves done reading kS/vS
        ushort* eT = (ushort*)smem + w * 2176;        // [16 q][136 dh-pad]
        float inv = 1.0f / lrow;
#pragma unroll
        for (int nt = 0; nt < 8; ++nt) {
            int dh = nt * 16 + quad * 4;
#pragma unroll
            for (int r = 0; r < 4; ++r)
                eT[l15 * 136 + dh + r] = f2bf(accO[nt][r] * inv);
        }
        for (int idx = lane; idx < 256; idx += 64) {
            int row = idx >> 4, c = idx & 15;
            uint4 v = *(const uint4*)(eT + row * 136 + c * 8);
            *(uint4*)(O + ((size_t)(b * T_) + q0 + w * 16 + row) * D_ + h * DH_ + c * 8) = v;
        }
    }
}

extern "C" void kernel_launch(void* const* d_in, const int* in_sizes, int n_in,
                              void* d_out, int out_size, void* d_ws, size_t ws_size,
                              hipStream_t stream) {
    const float* x  = (const float*)d_in[0];
    const float* Wq = (const float*)d_in[1];
    const float* bq = (const float*)d_in[2];
    const float* Wk = (const float*)d_in[3];
    const float* bk = (const float*)d_in[4];
    const float* Wv = (const float*)d_in[5];
    const float* bv = (const float*)d_in[6];
    const float* Wo = (const float*)d_in[7];
    const float* bo = (const float*)d_in[8];

    char* ws = (char*)d_ws;
    const size_t MB = 1u << 20;
    ushort* xb  = (ushort*)(ws);
    ushort* Wqt = (ushort*)(ws + 32 * MB);
    ushort* Wkt = (ushort*)(ws + 40 * MB);
    ushort* Wvt = (ushort*)(ws + 48 * MB);
    ushort* Wot = (ushort*)(ws + 56 * MB);
    ushort* Qb  = (ushort*)(ws + 64 * MB);
    ushort* Kb  = (ushort*)(ws + 96 * MB);
    ushort* Vtb = (ushort*)(ws + 128 * MB);
    ushort* Ob  = (ushort*)(ws + 160 * MB);

    const int M = B_ * T_;   // 8192
    const float qscale = (float)(0.08838834764831845 * 1.4426950408889634); // 1/sqrt(DH) * log2(e)

    cast_f32_bf16<<<(M * D_) / 1024, 256, 0, stream>>>(x, xb, M * D_);
    dim3 tb(32, 8), tg(D_ / 32, D_ / 32);
    transpose_cast<<<tg, tb, 0, stream>>>(Wq, Wqt);
    transpose_cast<<<tg, tb, 0, stream>>>(Wk, Wkt);
    transpose_cast<<<tg, tb, 0, stream>>>(Wv, Wvt);
    transpose_cast<<<tg, tb, 0, stream>>>(Wo, Wot);

    gemm_qkv<<<dim3(48, M / 128), 256, 34816, stream>>>(
        xb, Wqt, Wkt, Wvt, bq, bk, bv, Qb, Kb, Vtb, qscale);

    attn_kernel<<<dim3(1024), 256, 0, stream>>>(Qb, Kb, Vtb, Ob);

    gemm_bt_f32<<<dim3(D_ / 128, M / 128), 256, 16384, stream>>>(
        Ob, Wot, bo, (float*)d_out, M, D_, D_);
}